// Round 14
// baseline (903.502 us; speedup 1.0000x reference)
//
#include <hip/hip_runtime.h>
#include <hip/hip_bf16.h>
#include <hip/hip_fp16.h>

typedef _Float16 f16;
typedef _Float16 f16x2 __attribute__((ext_vector_type(2)));
typedef _Float16 f16x8 __attribute__((ext_vector_type(8)));
typedef float f32x4 __attribute__((ext_vector_type(4)));

#define HEADS 8
#define HID 64
#define NCLS 40
#define FEAT 512
#define BKT 256          // targets per bucket (bucket = src >> 8)
#define WINCAP 12288     // lds_place window capacity (ints)
#define STAGECAP 6656    // multisplit per-block edge chunk (52 KB LDS stage)

// ---------------- merged weight packing ----------------
__global__ void pack_all(const float* __restrict__ W, const float* __restrict__ Wp,
                         const float* __restrict__ Wo, const float* __restrict__ Wpo,
                         f16* __restrict__ Wh_t, f16* __restrict__ Bp_t,
                         f16* __restrict__ Wo_t, float* __restrict__ B2p) {
    int idx = blockIdx.x * blockDim.x + threadIdx.x;
    if (idx < 512 * 512) {
        int c = idx >> 9, k = idx & 511;
        Wh_t[idx] = (f16)W[(c >> 6) * 512 * 64 + k * 64 + (c & 63)];
    } else if (idx < 512 * 512 + 8 * 128 * 64) {
        int i = idx - 512 * 512;
        int head = i >> 13, c = (i >> 6) & 127, k = i & 63;
        Bp_t[i] = (f16)Wp[head * 8192 + ((c >> 6) * 64 + k) * 64 + (c & 63)];
    } else if (idx < 512 * 512 + 8 * 128 * 64 + 40 * 512) {
        int i = idx - (512 * 512 + 8 * 128 * 64);
        int c = i >> 9, k = i & 511;
        Wo_t[i] = (f16)Wo[k * 40 + c];
    } else if (idx < 512 * 512 + 8 * 128 * 64 + 40 * 512 + 40 * 80) {
        int i = idx - (512 * 512 + 8 * 128 * 64 + 40 * 512);
        int k = i / 80, c = i % 80;
        int p = c / 40, j = c % 40;
        B2p[i] = Wpo[(p * 40 + k) * 40 + j];
    }
}

// vh2[t][k] = {f16(v2[t][k]), f16(h2[t][k])}
__global__ void pack_vh2(const float* __restrict__ h2, const float* __restrict__ uv2,
                         f16x2* __restrict__ vh2, int total) {
    int i = blockIdx.x * blockDim.x + threadIdx.x;
    if (i >= total) return;
    int t = i / 40, k = i % 40;
    vh2[i] = f16x2{(f16)uv2[(size_t)t * 80 + 40 + k], (f16)h2[i]};
}

// ---------------- CSR build ----------------
__global__ void hist_kernel(const int* __restrict__ src, int* __restrict__ counts, int ne) {
    int i = blockIdx.x * blockDim.x + threadIdx.x;
    int stride = gridDim.x * blockDim.x;
    for (; i < ne; i += stride) atomicAdd(&counts[src[i]], 1);
}

__global__ void scan_partial(const int* __restrict__ counts, int* __restrict__ partial, int n) {
    __shared__ int s[256];
    int i = blockIdx.x * 256 + threadIdx.x;
    s[threadIdx.x] = (i < n) ? counts[i] : 0;
    __syncthreads();
    for (int d = 128; d > 0; d >>= 1) {
        if (threadIdx.x < d) s[threadIdx.x] += s[threadIdx.x + d];
        __syncthreads();
    }
    if (threadIdx.x == 0) partial[blockIdx.x] = s[0];
}

__global__ void scan_top(int* __restrict__ partial, int nb) {
    __shared__ int s[1024];
    int tid = threadIdx.x;
    s[tid] = (tid < nb) ? partial[tid] : 0;
    __syncthreads();
    for (int d = 1; d < 1024; d <<= 1) {
        int v = (tid >= d) ? s[tid - d] : 0;
        __syncthreads();
        s[tid] += v;
        __syncthreads();
    }
    if (tid < nb) partial[tid] = (tid == 0) ? 0 : s[tid - 1];
}

__global__ void scan_final(const int* __restrict__ counts, const int* __restrict__ partialEx,
                           int* __restrict__ offsets, int n) {
    __shared__ int s[256];
    int i = blockIdx.x * 256 + threadIdx.x;
    int v = (i < n) ? counts[i] : 0;
    s[threadIdx.x] = v;
    __syncthreads();
    for (int d = 1; d < 256; d <<= 1) {
        int u = (threadIdx.x >= d) ? s[threadIdx.x - d] : 0;
        __syncthreads();
        s[threadIdx.x] += u;
        __syncthreads();
    }
    int excl = partialEx[blockIdx.x] + s[threadIdx.x] - v;
    if (i < n) {
        offsets[i] = excl;
        if (i == n - 1) offsets[n] = excl + v;
    }
}

__global__ void binit(const int* __restrict__ offsets, int* __restrict__ bcursor, int nbuckets) {
    int b = blockIdx.x * blockDim.x + threadIdx.x;
    if (b < nbuckets) bcursor[b] = offsets[b * BKT];
}

// stage 1: privatized multisplit
__global__ void multisplit(const int* __restrict__ src, const int* __restrict__ dst,
                           int* __restrict__ bcursor, uint2* __restrict__ pairs,
                           int ne, int nbuckets) {
    __shared__ int lcnt[256], lscan[256], lbase[256], lpos[256];
    __shared__ uint2 stage[STAGECAP];
    const int chunk = (ne + gridDim.x - 1) / gridDim.x;
    const int e0 = blockIdx.x * chunk;
    const int e1 = (e0 + chunk < ne) ? e0 + chunk : ne;
    const int tid = threadIdx.x;
    if (e0 >= ne) return;
    const int m = e1 - e0;
    lcnt[tid] = 0;
    __syncthreads();
    for (int i = e0 + tid; i < e1; i += 256)
        atomicAdd(&lcnt[(unsigned)src[i] >> 8], 1);
    __syncthreads();
    int v = lcnt[tid];
    lscan[tid] = v;
    __syncthreads();
    for (int d = 1; d < 256; d <<= 1) {
        int u = (tid >= d) ? lscan[tid - d] : 0;
        __syncthreads();
        lscan[tid] += u;
        __syncthreads();
    }
    int excl = lscan[tid] - v;
    __syncthreads();
    lscan[tid] = excl;
    lpos[tid] = excl;
    if (tid < nbuckets && v > 0) lbase[tid] = atomicAdd(&bcursor[tid], v);
    __syncthreads();
    for (int i = e0 + tid; i < e1; i += 256) {
        unsigned s = (unsigned)src[i];
        int b = s >> 8;
        int p = atomicAdd(&lpos[b], 1);
        stage[p] = uint2{s, (unsigned)dst[i]};
    }
    __syncthreads();
    for (int i = tid; i < m; i += 256) {
        uint2 pr = stage[i];
        int b = pr.x >> 8;
        pairs[lbase[b] + (i - lscan[b])] = pr;
    }
}

// stage 2: per-bucket LDS placement
__global__ void lds_place(const uint2* __restrict__ pairs, const int* __restrict__ offsets,
                          int* __restrict__ dsts, int n) {
    __shared__ int cnt[BKT];
    __shared__ int win[WINCAP];
    const int b = blockIdx.x;
    const int t0 = b * BKT;
    const int t1 = (t0 + BKT < n) ? t0 + BKT : n;
    const int base = offsets[t0];
    const int end = offsets[t1];
    const int m = end - base;
    for (int t = threadIdx.x; t < t1 - t0; t += blockDim.x) cnt[t] = offsets[t0 + t] - base;
    __syncthreads();
    if (m <= WINCAP) {
        for (int i = threadIdx.x; i < m; i += blockDim.x) {
            uint2 p = pairs[base + i];
            int pos = atomicAdd(&cnt[p.x - (unsigned)t0], 1);
            win[pos] = (int)p.y;
        }
        __syncthreads();
        for (int i = threadIdx.x; i < m; i += blockDim.x) dsts[base + i] = win[i];
    } else {
        for (int i = threadIdx.x; i < m; i += blockDim.x) {
            uint2 p = pairs[base + i];
            int pos = atomicAdd(&cnt[p.x - (unsigned)t0], 1);
            dsts[base + pos] = (int)p.y;
        }
    }
}

// ---------------- MFMA f16 GEMM: 128xTC tile, BK=32, 4 waves (2x2) ----------------
__device__ __forceinline__ void stC(float* p, float v) { *p = v; }
__device__ __forceinline__ void stC(f16* p, float v) { *p = (f16)v; }
__device__ __forceinline__ f16x8 ldA8(const f16* p) { return *(const f16x8*)p; }
__device__ __forceinline__ f16x8 ldA8(const float* p) {
    float4 a = ((const float4*)p)[0];
    float4 b = ((const float4*)p)[1];
    f16x8 r = {(f16)a.x, (f16)a.y, (f16)a.z, (f16)a.w, (f16)b.x, (f16)b.y, (f16)b.z, (f16)b.w};
    return r;
}

template <int TC, typename AT, typename CT>
__global__ __launch_bounds__(256)
void gemm_mfma(const AT* __restrict__ A, int lda, int acol0, int acolStride,
               const f16* __restrict__ Bt, long bBatchStride, int K,
               CT* __restrict__ C, int ldc, int ccolStride,
               int nrows, int ncols) {
    constexpr int NJ = TC / 32;            // j-frags per wave (wave spans TC/2 cols)
    __shared__ f16 As[128][40];
    __shared__ f16 Bs[TC][40];
    const int batch = blockIdx.y;
    const int row0 = blockIdx.x * 128;
    const int col0 = blockIdx.z * TC;
    const int a0 = acol0 + batch * acolStride;
    const f16* Bb = Bt + (size_t)batch * bBatchStride;
    const int tid = threadIdx.x;
    const int lane = tid & 63;
    const int wave = tid >> 6;
    const int wr = (wave >> 1) * 64;
    const int wc = (wave & 1) * (TC / 2);
    f32x4 acc[4][NJ] = {};

    for (int k0 = 0; k0 < K; k0 += 32) {
#pragma unroll
        for (int i = 0; i < 2; i++) {
            int idx = tid + i * 256;
            int r = idx >> 2, ch = idx & 3;
            int gr = row0 + r;
            f16x8 val = {};
            if (gr < nrows) val = ldA8(A + (size_t)gr * lda + a0 + k0 + ch * 8);
            *(f16x8*)(&As[r][ch * 8]) = val;
        }
#pragma unroll
        for (int i = 0; i < TC / 64; i++) {
            int idx = tid + i * 256;
            int r = idx >> 2, ch = idx & 3;
            int gc = col0 + r;
            f16x8 val = {};
            if (gc < ncols) val = *(const f16x8*)(Bb + (size_t)gc * K + k0 + ch * 8);
            *(f16x8*)(&Bs[r][ch * 8]) = val;
        }
        __syncthreads();
        f16x8 af[4], bf[NJ];
#pragma unroll
        for (int t = 0; t < 4; t++)
            af[t] = *(const f16x8*)(&As[wr + t * 16 + (lane & 15)][(lane >> 4) * 8]);
#pragma unroll
        for (int t = 0; t < NJ; t++)
            bf[t] = *(const f16x8*)(&Bs[wc + t * 16 + (lane & 15)][(lane >> 4) * 8]);
#pragma unroll
        for (int i = 0; i < 4; i++)
#pragma unroll
            for (int j = 0; j < NJ; j++)
                acc[i][j] = __builtin_amdgcn_mfma_f32_16x16x32_f16(af[i], bf[j], acc[i][j], 0, 0, 0);
        __syncthreads();
    }
    const int crow = (lane >> 4) * 4;
    const int ccol = lane & 15;
#pragma unroll
    for (int i = 0; i < 4; i++) {
#pragma unroll
        for (int j = 0; j < NJ; j++) {
            int gc = col0 + wc + j * 16 + ccol;
            if (gc >= ncols) continue;
#pragma unroll
            for (int r = 0; r < 4; r++) {
                int gr = row0 + wr + i * 16 + crow + r;
                if (gr < nrows)
                    stC(&C[(size_t)gr * ldc + (size_t)batch * ccolStride + gc], acc[i][j][r]);
            }
        }
    }
}

// ---------------- tiny fp32 vector GEMM (uv2: K=40, N=80) ----------------
__global__ void gemm_kernel(const float* __restrict__ A, int lda,
                            const float* __restrict__ B, int ldb,
                            float* __restrict__ C, int ldc,
                            int nrows, int K, int ncols) {
    __shared__ __align__(16) float As[16][68];
    __shared__ __align__(16) float Bs[16][64];
    const int colblk = blockIdx.z * 64;
    const int row0 = blockIdx.x * 64;
    const int tid = threadIdx.x;
    const int tm = tid >> 4, tn = tid & 15;
    float acc[4][4] = {};
    for (int k0 = 0; k0 < K; k0 += 16) {
#pragma unroll
        for (int i = 0; i < 4; i++) {
            int idx = tid + i * 256;
            int m = idx >> 4;
            int k = idx & 15;
            int gr = row0 + m;
            float v = 0.f;
            if (gr < nrows && (k0 + k) < K) v = A[(size_t)gr * lda + k0 + k];
            As[k][m] = v;
        }
#pragma unroll
        for (int i = 0; i < 4; i++) {
            int idx = tid + i * 256;
            int k = idx >> 6;
            int j = idx & 63;
            float v = 0.f;
            if ((k0 + k) < K && (colblk + j) < ncols) v = B[(size_t)(k0 + k) * ldb + colblk + j];
            Bs[k][j] = v;
        }
        __syncthreads();
#pragma unroll
        for (int k = 0; k < 16; k++) {
            float av[4], bv[4];
#pragma unroll
            for (int i = 0; i < 4; i++) av[i] = As[k][tm * 4 + i];
#pragma unroll
            for (int j = 0; j < 4; j++) bv[j] = Bs[k][tn * 4 + j];
#pragma unroll
            for (int i = 0; i < 4; i++)
#pragma unroll
                for (int j = 0; j < 4; j++) acc[i][j] += av[i] * bv[j];
        }
        __syncthreads();
    }
#pragma unroll
    for (int i = 0; i < 4; i++) {
        int gr = row0 + tm * 4 + i;
        if (gr >= nrows) continue;
#pragma unroll
        for (int j = 0; j < 4; j++) {
            int gc = colblk + tn * 4 + j;
            if (gc < ncols) C[(size_t)gr * ldc + gc] = acc[i][j];
        }
    }
}

// ---------------- helpers ----------------
__device__ __forceinline__ void store8h(f16* p, const float o[8]) {
    f16x8 v;
#pragma unroll
    for (int k = 0; k < 8; k++) v[k] = (f16)o[k];
    *(f16x8*)p = v;
}

__device__ __forceinline__ float dot8_lrelu(const uint4& vr, const f16x2 u2[4],
                                            const f16x2 a2[4]) {
    const f16x2* vp = (const f16x2*)&vr;
    float p = 0.f;
#pragma unroll
    for (int k = 0; k < 4; k++) {
        f16x2 w = u2[k] + vp[k];
        f16x2 lr = __builtin_elementwise_max(w, w * (_Float16)0.2f);
#if __has_builtin(__builtin_amdgcn_fdot2)
        p = __builtin_amdgcn_fdot2(lr, a2[k], p, false);
#else
        p = fmaf((float)lr[0], (float)a2[k][0], p);
        p = fmaf((float)lr[1], (float)a2[k][1], p);
#endif
    }
    return p;
}

// ---------------- layer-1 edge/aggregation (fused, single launch) ----------------
__global__ void edge_l1(const int* __restrict__ offsets, const int* __restrict__ dsts,
                        const f16* __restrict__ h, const f16* __restrict__ uv,
                        const float* __restrict__ a, f16* __restrict__ x2, int n) {
    const int lane = threadIdx.x & 63;
    const int wave = threadIdx.x >> 6;
    const int t = blockIdx.x * (blockDim.x >> 6) + wave;
    if (t >= n) return;
    const int head = lane >> 3;
    const int sub = lane & 7;
    const unsigned voff = head * 128 + 64 + sub * 8;
    const unsigned uoff = head * 128 + sub * 8;
    const unsigned hoff = lane * 8;

    f16x2 u2[4], a2[4];
    {
        uint4 ur = *(const uint4*)(uv + (size_t)t * 1024 + uoff);
        const f16x2* up = (const f16x2*)&ur;
#pragma unroll
        for (int k = 0; k < 4; k++) u2[k] = up[k];
        const float4* ap = (const float4*)(a + hoff);
        float4 a0 = ap[0], a1 = ap[1];
        a2[0] = f16x2{(f16)a0.x, (f16)a0.y};
        a2[1] = f16x2{(f16)a0.z, (f16)a0.w};
        a2[2] = f16x2{(f16)a1.x, (f16)a1.y};
        a2[3] = f16x2{(f16)a1.z, (f16)a1.w};
    }

    const int s0 = offsets[t], s1 = offsets[t + 1];
    float acc[8] = {0.f, 0.f, 0.f, 0.f, 0.f, 0.f, 0.f, 0.f};
    float rs = 0.f;

    for (int base = s0; base < s1; base += 64) {
        int cnt = s1 - base;
        if (cnt > 64) cnt = 64;
        int myd = (lane < cnt) ? dsts[base + lane] : 0;
        int d0 = __shfl(myd, 0, 64);
        uint4 vr = *(const uint4*)(uv + (size_t)(unsigned)d0 * 1024 + voff);
        uint4 hr = *(const uint4*)(h + (size_t)(unsigned)d0 * 512 + hoff);
        for (int j = 0; j < cnt; j++) {
            uint4 vr_n, hr_n;
            if (j + 1 < cnt) {
                int dn = __shfl(myd, j + 1, 64);
                vr_n = *(const uint4*)(uv + (size_t)(unsigned)dn * 1024 + voff);
                hr_n = *(const uint4*)(h + (size_t)(unsigned)dn * 512 + hoff);
            }
            float p = dot8_lrelu(vr, u2, a2);
            p += __shfl_xor(p, 1, 64);
            p += __shfl_xor(p, 2, 64);
            p += __shfl_xor(p, 4, 64);
            float wgt = __expf(p);
            rs += wgt;
            const f16* hp = (const f16*)&hr;
#pragma unroll
            for (int k = 0; k < 8; k++) acc[k] = fmaf(wgt, (float)hp[k], acc[k]);
            vr = vr_n;
            hr = hr_n;
        }
    }
    float inv = 1.f / rs;
    float o[8];
#pragma unroll
    for (int k = 0; k < 8; k++) {
        float hp = acc[k] * inv;
        float e1 = hp > 0.f ? hp : expm1f(hp);
        o[k] = e1 > 0.f ? e1 : expm1f(e1);
    }
    store8h(x2 + (size_t)t * 512 + hoff, o);
}

// ---------------- layer-2 edge/aggregation: 8 edges in flight per wave ----------------
// lane s handles columns {k*8+s}: each k-step is a 32B-coalesced segment per 8-lane group.
__global__ void edge_l2(const int* __restrict__ offsets, const int* __restrict__ dsts,
                        const f16x2* __restrict__ vh2, const float* __restrict__ uv2,
                        const float* __restrict__ a_out, float* __restrict__ out, int n) {
    const int lane = threadIdx.x & 63;
    const int wave = threadIdx.x >> 6;
    const int t = blockIdx.x * (blockDim.x >> 6) + wave;
    if (t >= n) return;
    const int g = lane >> 3;
    const int s = lane & 7;
    float u5[5], a5[5];
#pragma unroll
    for (int k = 0; k < 5; k++) {
        u5[k] = uv2[(size_t)t * 80 + k * 8 + s];
        a5[k] = a_out[k * 8 + s];
    }
    const int s0 = offsets[t], s1 = offsets[t + 1];
    float acc[5] = {0.f, 0.f, 0.f, 0.f, 0.f};
    float rs = 0.f;
    for (int base = s0; base < s1; base += 64) {
        int cnt = s1 - base;
        if (cnt > 64) cnt = 64;
        int myd = (lane < cnt) ? dsts[base + lane] : 0;
        for (int j8 = 0; j8 < cnt; j8 += 8) {
            int eidx = j8 + g;
            bool active = eidx < cnt;
            int d = __shfl(myd, active ? eidx : 0, 64);
            f16x2 vh[5];
            const f16x2* vp = vh2 + (size_t)(unsigned)d * 40 + s;
#pragma unroll
            for (int k = 0; k < 5; k++) vh[k] = vp[k * 8];
            float p = 0.f;
#pragma unroll
            for (int k = 0; k < 5; k++) {
                float w = u5[k] + (float)vh[k][0];
                p = fmaf(a5[k], fmaxf(w, 0.2f * w), p);
            }
            p += __shfl_xor(p, 1, 64);
            p += __shfl_xor(p, 2, 64);
            p += __shfl_xor(p, 4, 64);
            float wgt = active ? __expf(p) : 0.f;
            rs += wgt;
#pragma unroll
            for (int k = 0; k < 5; k++) acc[k] = fmaf(wgt, (float)vh[k][1], acc[k]);
        }
    }
    rs += __shfl_xor(rs, 8, 64);
    rs += __shfl_xor(rs, 16, 64);
    rs += __shfl_xor(rs, 32, 64);
#pragma unroll
    for (int k = 0; k < 5; k++) {
        acc[k] += __shfl_xor(acc[k], 8, 64);
        acc[k] += __shfl_xor(acc[k], 16, 64);
        acc[k] += __shfl_xor(acc[k], 32, 64);
    }
    if (g == 0) {
        float inv = 1.f / rs;
#pragma unroll
        for (int k = 0; k < 5; k++) {
            float hp = acc[k] * inv;
            out[(size_t)t * 40 + k * 8 + s] = hp > 0.f ? hp : expm1f(hp);
        }
    }
}

// ---------------- launch ----------------
extern "C" void kernel_launch(void* const* d_in, const int* in_sizes, int n_in,
                              void* d_out, int out_size, void* d_ws, size_t ws_size,
                              hipStream_t stream) {
    const float* x         = (const float*)d_in[0];
    const int*   edge      = (const int*)d_in[1];
    const float* W         = (const float*)d_in[2];
    const float* W_pair    = (const float*)d_in[3];
    const float* a         = (const float*)d_in[4];
    const float* W_out     = (const float*)d_in[5];
    const float* W_pair_out= (const float*)d_in[6];
    const float* a_out     = (const float*)d_in[7];
    float* out = (float*)d_out;

    const int n  = in_sizes[0] / FEAT;   // 50000
    const int ne = in_sizes[1] / 2;      // 1,650,000
    const int* srcArr = edge;
    const int* dstArr = edge + ne;

    char* ws = (char*)d_ws;
    size_t off = 0;
    auto alloc = [&](size_t bytes) -> void* {
        void* p = ws + off;
        off = (off + bytes + 255) & ~(size_t)255;
        return p;
    };
    f16* h    = (f16*)alloc((size_t)n * 512 * sizeof(f16));      // [N][512]; later aliased by h2/uv2
    f16* uv   = (f16*)alloc((size_t)n * 1024 * sizeof(f16));     // [N][1024]
    f16* x2   = (f16*)alloc((size_t)n * 512 * sizeof(f16));      // [N][512]
    f16x2* vh2 = (f16x2*)alloc((size_t)n * 40 * sizeof(f16x2));  // [N][40] {v2,h2}
    uint2* pairs = (uint2*)alloc((size_t)ne * sizeof(uint2));    // [E] (src,dst) bucket-ordered
    f16* Wh_t = (f16*)alloc(512 * 512 * sizeof(f16));
    f16* Bp_t = (f16*)alloc(8 * 128 * 64 * sizeof(f16));
    f16* Wo_t = (f16*)alloc(40 * 512 * sizeof(f16));
    float* B2p = (float*)alloc(40 * 80 * sizeof(float));
    int* counts  = (int*)alloc((size_t)n * sizeof(int));
    int* offsets = (int*)alloc((size_t)(n + 1) * sizeof(int));
    int* bcursor = (int*)alloc(1024 * sizeof(int));
    int* partial = (int*)alloc(1024 * sizeof(int));
    int* dsts    = (int*)alloc((size_t)ne * sizeof(int));
    float* h2  = (float*)h;                          // h dead after edge_l1
    float* uv2 = (float*)((char*)h + (size_t)n * 40 * sizeof(float));

    const int nb = (n + 255) / 256;             // 196 scan blocks
    const int nbuckets = (n + BKT - 1) / BKT;   // 196
    const int msBlocks = (ne + STAGECAP - 1) / STAGECAP;   // 248

    // CSR build: hist -> scan -> multisplit (bucket order) -> LDS place (target order)
    hipMemsetAsync(counts, 0, (size_t)n * sizeof(int), stream);
    hist_kernel<<<2048, 256, 0, stream>>>(srcArr, counts, ne);
    scan_partial<<<nb, 256, 0, stream>>>(counts, partial, n);
    scan_top<<<1, 1024, 0, stream>>>(partial, nb);
    scan_final<<<nb, 256, 0, stream>>>(counts, partial, offsets, n);
    binit<<<(nbuckets + 255) / 256, 256, 0, stream>>>(offsets, bcursor, nbuckets);
    multisplit<<<msBlocks, 256, 0, stream>>>(srcArr, dstArr, bcursor, pairs, ne, nbuckets);
    lds_place<<<nbuckets, 256, 0, stream>>>(pairs, offsets, dsts, n);

    // weight packs (single launch)
    const int packTotal = 512 * 512 + 8 * 128 * 64 + 40 * 512 + 40 * 80;
    pack_all<<<(packTotal + 255) / 256, 256, 0, stream>>>(
        W, W_pair, W_out, W_pair_out, Wh_t, Bp_t, Wo_t, B2p);

    const int mBlocks = (n + 127) / 128;   // 391

    // h = f16(x) @ Wh   [N,512] f16  (256-wide col-blocks: halves f32 A re-reads)
    gemm_mfma<256, float, f16><<<dim3(mBlocks, 1, 2), 256, 0, stream>>>(
        x, 512, 0, 0, Wh_t, 0, 512, h, 512, 0, n, 512);

    // uv = per-head h @ Bp_t   (K=64)
    gemm_mfma<128, f16, f16><<<dim3(mBlocks, 8, 1), 256, 0, stream>>>(
        h, 512, 0, 64, Bp_t, 128L * 64, 64, uv, 1024, 128, n, 128);

    // layer-1 edge phase -> x2 (single launch)
    edge_l1<<<dim3((n + 3) / 4), 256, 0, stream>>>(offsets, dsts, h, uv, a, x2, n);

    // h2 = x2 @ W_out  [N,40] f32 (aliases h)
    gemm_mfma<128, f16, float><<<dim3(mBlocks, 1, 1), 256, 0, stream>>>(
        x2, 512, 0, 0, Wo_t, 0, 512, h2, 40, 0, n, 40);

    // uv2 = h2 @ B2p  [N,80] f32
    gemm_kernel<<<dim3((n + 63) / 64, 1, 2), 256, 0, stream>>>(
        h2, 40, B2p, 80, uv2, 80, n, 40, 80);

    // pack interleaved {v2,h2} f16 pairs for edge_l2
    pack_vh2<<<(n * 40 + 255) / 256, 256, 0, stream>>>(h2, uv2, vh2, n * 40);

    // layer-2 edge phase -> out
    edge_l2<<<dim3((n + 3) / 4), 256, 0, stream>>>(offsets, dsts, vh2, uv2, a_out, out, n);
}

// Round 15
// 853.032 us; speedup vs baseline: 1.0592x; 1.0592x over previous
//
#include <hip/hip_runtime.h>
#include <hip/hip_bf16.h>
#include <hip/hip_fp16.h>

typedef _Float16 f16;
typedef _Float16 f16x2 __attribute__((ext_vector_type(2)));
typedef _Float16 f16x8 __attribute__((ext_vector_type(8)));
typedef float f32x4 __attribute__((ext_vector_type(4)));

#define HEADS 8
#define HID 64
#define NCLS 40
#define FEAT 512
#define BKT 256          // targets per bucket (bucket = src >> 8)
#define WINCAP 12288     // lds_place window capacity (ints)
#define STAGECAP 6656    // multisplit per-block edge chunk (52 KB LDS stage)

// ---------------- merged weight packing ----------------
__global__ void pack_all(const float* __restrict__ W, const float* __restrict__ Wp,
                         const float* __restrict__ Wo, const float* __restrict__ Wpo,
                         f16* __restrict__ Wh_t, f16* __restrict__ Bp_t,
                         f16* __restrict__ Wo_t, float* __restrict__ B2p) {
    int idx = blockIdx.x * blockDim.x + threadIdx.x;
    if (idx < 512 * 512) {
        int c = idx >> 9, k = idx & 511;
        Wh_t[idx] = (f16)W[(c >> 6) * 512 * 64 + k * 64 + (c & 63)];
    } else if (idx < 512 * 512 + 8 * 128 * 64) {
        int i = idx - 512 * 512;
        int head = i >> 13, c = (i >> 6) & 127, k = i & 63;
        Bp_t[i] = (f16)Wp[head * 8192 + ((c >> 6) * 64 + k) * 64 + (c & 63)];
    } else if (idx < 512 * 512 + 8 * 128 * 64 + 40 * 512) {
        int i = idx - (512 * 512 + 8 * 128 * 64);
        int c = i >> 9, k = i & 511;
        Wo_t[i] = (f16)Wo[k * 40 + c];
    } else if (idx < 512 * 512 + 8 * 128 * 64 + 40 * 512 + 40 * 80) {
        int i = idx - (512 * 512 + 8 * 128 * 64 + 40 * 512);
        int k = i / 80, c = i % 80;
        int p = c / 40, j = c % 40;
        B2p[i] = Wpo[(p * 40 + k) * 40 + j];
    }
}

// vh2[t][k] = {f16(v2[t][k]), f16(h2[t][k])}
__global__ void pack_vh2(const float* __restrict__ h2, const float* __restrict__ uv2,
                         f16x2* __restrict__ vh2, int total) {
    int i = blockIdx.x * blockDim.x + threadIdx.x;
    if (i >= total) return;
    int t = i / 40, k = i % 40;
    vh2[i] = f16x2{(f16)uv2[(size_t)t * 80 + 40 + k], (f16)h2[i]};
}

// ---------------- CSR build ----------------
__global__ void hist_kernel(const int* __restrict__ src, int* __restrict__ counts, int ne) {
    int i = blockIdx.x * blockDim.x + threadIdx.x;
    int stride = gridDim.x * blockDim.x;
    for (; i < ne; i += stride) atomicAdd(&counts[src[i]], 1);
}

__global__ void scan_partial(const int* __restrict__ counts, int* __restrict__ partial, int n) {
    __shared__ int s[256];
    int i = blockIdx.x * 256 + threadIdx.x;
    s[threadIdx.x] = (i < n) ? counts[i] : 0;
    __syncthreads();
    for (int d = 128; d > 0; d >>= 1) {
        if (threadIdx.x < d) s[threadIdx.x] += s[threadIdx.x + d];
        __syncthreads();
    }
    if (threadIdx.x == 0) partial[blockIdx.x] = s[0];
}

__global__ void scan_top(int* __restrict__ partial, int nb) {
    __shared__ int s[1024];
    int tid = threadIdx.x;
    s[tid] = (tid < nb) ? partial[tid] : 0;
    __syncthreads();
    for (int d = 1; d < 1024; d <<= 1) {
        int v = (tid >= d) ? s[tid - d] : 0;
        __syncthreads();
        s[tid] += v;
        __syncthreads();
    }
    if (tid < nb) partial[tid] = (tid == 0) ? 0 : s[tid - 1];
}

__global__ void scan_final(const int* __restrict__ counts, const int* __restrict__ partialEx,
                           int* __restrict__ offsets, int n) {
    __shared__ int s[256];
    int i = blockIdx.x * 256 + threadIdx.x;
    int v = (i < n) ? counts[i] : 0;
    s[threadIdx.x] = v;
    __syncthreads();
    for (int d = 1; d < 256; d <<= 1) {
        int u = (threadIdx.x >= d) ? s[threadIdx.x - d] : 0;
        __syncthreads();
        s[threadIdx.x] += u;
        __syncthreads();
    }
    int excl = partialEx[blockIdx.x] + s[threadIdx.x] - v;
    if (i < n) {
        offsets[i] = excl;
        if (i == n - 1) offsets[n] = excl + v;
    }
}

__global__ void binit(const int* __restrict__ offsets, int* __restrict__ bcursor, int nbuckets) {
    int b = blockIdx.x * blockDim.x + threadIdx.x;
    if (b < nbuckets) bcursor[b] = offsets[b * BKT];
}

// stage 1: privatized multisplit
__global__ void multisplit(const int* __restrict__ src, const int* __restrict__ dst,
                           int* __restrict__ bcursor, uint2* __restrict__ pairs,
                           int ne, int nbuckets) {
    __shared__ int lcnt[256], lscan[256], lbase[256], lpos[256];
    __shared__ uint2 stage[STAGECAP];
    const int chunk = (ne + gridDim.x - 1) / gridDim.x;
    const int e0 = blockIdx.x * chunk;
    const int e1 = (e0 + chunk < ne) ? e0 + chunk : ne;
    const int tid = threadIdx.x;
    if (e0 >= ne) return;
    const int m = e1 - e0;
    lcnt[tid] = 0;
    __syncthreads();
    for (int i = e0 + tid; i < e1; i += 256)
        atomicAdd(&lcnt[(unsigned)src[i] >> 8], 1);
    __syncthreads();
    int v = lcnt[tid];
    lscan[tid] = v;
    __syncthreads();
    for (int d = 1; d < 256; d <<= 1) {
        int u = (tid >= d) ? lscan[tid - d] : 0;
        __syncthreads();
        lscan[tid] += u;
        __syncthreads();
    }
    int excl = lscan[tid] - v;
    __syncthreads();
    lscan[tid] = excl;
    lpos[tid] = excl;
    if (tid < nbuckets && v > 0) lbase[tid] = atomicAdd(&bcursor[tid], v);
    __syncthreads();
    for (int i = e0 + tid; i < e1; i += 256) {
        unsigned s = (unsigned)src[i];
        int b = s >> 8;
        int p = atomicAdd(&lpos[b], 1);
        stage[p] = uint2{s, (unsigned)dst[i]};
    }
    __syncthreads();
    for (int i = tid; i < m; i += 256) {
        uint2 pr = stage[i];
        int b = pr.x >> 8;
        pairs[lbase[b] + (i - lscan[b])] = pr;
    }
}

// stage 2: per-bucket LDS placement
__global__ void lds_place(const uint2* __restrict__ pairs, const int* __restrict__ offsets,
                          int* __restrict__ dsts, int n) {
    __shared__ int cnt[BKT];
    __shared__ int win[WINCAP];
    const int b = blockIdx.x;
    const int t0 = b * BKT;
    const int t1 = (t0 + BKT < n) ? t0 + BKT : n;
    const int base = offsets[t0];
    const int end = offsets[t1];
    const int m = end - base;
    for (int t = threadIdx.x; t < t1 - t0; t += blockDim.x) cnt[t] = offsets[t0 + t] - base;
    __syncthreads();
    if (m <= WINCAP) {
        for (int i = threadIdx.x; i < m; i += blockDim.x) {
            uint2 p = pairs[base + i];
            int pos = atomicAdd(&cnt[p.x - (unsigned)t0], 1);
            win[pos] = (int)p.y;
        }
        __syncthreads();
        for (int i = threadIdx.x; i < m; i += blockDim.x) dsts[base + i] = win[i];
    } else {
        for (int i = threadIdx.x; i < m; i += blockDim.x) {
            uint2 p = pairs[base + i];
            int pos = atomicAdd(&cnt[p.x - (unsigned)t0], 1);
            dsts[base + pos] = (int)p.y;
        }
    }
}

// ---------------- MFMA f16 GEMM: 128x128 tile, BK=32, 4 waves ----------------
__device__ __forceinline__ void stC(float* p, float v) { *p = v; }
__device__ __forceinline__ void stC(f16* p, float v) { *p = (f16)v; }
__device__ __forceinline__ f16x8 ldA8(const f16* p) { return *(const f16x8*)p; }
__device__ __forceinline__ f16x8 ldA8(const float* p) {
    float4 a = ((const float4*)p)[0];
    float4 b = ((const float4*)p)[1];
    f16x8 r = {(f16)a.x, (f16)a.y, (f16)a.z, (f16)a.w, (f16)b.x, (f16)b.y, (f16)b.z, (f16)b.w};
    return r;
}

template <typename AT, typename CT>
__global__ __launch_bounds__(256)
void gemm_mfma(const AT* __restrict__ A, int lda, int acol0, int acolStride,
               const f16* __restrict__ Bt, long bBatchStride, int K,
               CT* __restrict__ C, int ldc, int ccolStride,
               int nrows, int ncols) {
    __shared__ f16 As[128][40];
    __shared__ f16 Bs[128][40];
    const int batch = blockIdx.y;
    const int row0 = blockIdx.x * 128;
    const int col0 = blockIdx.z * 128;
    const int a0 = acol0 + batch * acolStride;
    const f16* Bb = Bt + (size_t)batch * bBatchStride;
    const int tid = threadIdx.x;
    const int lane = tid & 63;
    const int wave = tid >> 6;
    const int wr = (wave >> 1) * 64;
    const int wc = (wave & 1) * 64;
    f32x4 acc[4][4] = {};

    for (int k0 = 0; k0 < K; k0 += 32) {
#pragma unroll
        for (int i = 0; i < 2; i++) {
            int idx = tid + i * 256;
            int r = idx >> 2, ch = idx & 3;
            int gr = row0 + r;
            f16x8 val = {};
            if (gr < nrows) val = ldA8(A + (size_t)gr * lda + a0 + k0 + ch * 8);
            *(f16x8*)(&As[r][ch * 8]) = val;
        }
#pragma unroll
        for (int i = 0; i < 2; i++) {
            int idx = tid + i * 256;
            int r = idx >> 2, ch = idx & 3;
            int gc = col0 + r;
            f16x8 val = {};
            if (gc < ncols) val = *(const f16x8*)(Bb + (size_t)gc * K + k0 + ch * 8);
            *(f16x8*)(&Bs[r][ch * 8]) = val;
        }
        __syncthreads();
        f16x8 af[4], bf[4];
#pragma unroll
        for (int t = 0; t < 4; t++)
            af[t] = *(const f16x8*)(&As[wr + t * 16 + (lane & 15)][(lane >> 4) * 8]);
#pragma unroll
        for (int t = 0; t < 4; t++)
            bf[t] = *(const f16x8*)(&Bs[wc + t * 16 + (lane & 15)][(lane >> 4) * 8]);
#pragma unroll
        for (int i = 0; i < 4; i++)
#pragma unroll
            for (int j = 0; j < 4; j++)
                acc[i][j] = __builtin_amdgcn_mfma_f32_16x16x32_f16(af[i], bf[j], acc[i][j], 0, 0, 0);
        __syncthreads();
    }
    const int crow = (lane >> 4) * 4;
    const int ccol = lane & 15;
#pragma unroll
    for (int i = 0; i < 4; i++) {
#pragma unroll
        for (int j = 0; j < 4; j++) {
            int gc = col0 + wc + j * 16 + ccol;
            if (gc >= ncols) continue;
#pragma unroll
            for (int r = 0; r < 4; r++) {
                int gr = row0 + wr + i * 16 + crow + r;
                if (gr < nrows)
                    stC(&C[(size_t)gr * ldc + (size_t)batch * ccolStride + gc], acc[i][j][r]);
            }
        }
    }
}

// ---------------- tiny fp32 vector GEMM (uv2: K=40, N=80) ----------------
__global__ void gemm_kernel(const float* __restrict__ A, int lda,
                            const float* __restrict__ B, int ldb,
                            float* __restrict__ C, int ldc,
                            int nrows, int K, int ncols) {
    __shared__ __align__(16) float As[16][68];
    __shared__ __align__(16) float Bs[16][64];
    const int colblk = blockIdx.z * 64;
    const int row0 = blockIdx.x * 64;
    const int tid = threadIdx.x;
    const int tm = tid >> 4, tn = tid & 15;
    float acc[4][4] = {};
    for (int k0 = 0; k0 < K; k0 += 16) {
#pragma unroll
        for (int i = 0; i < 4; i++) {
            int idx = tid + i * 256;
            int m = idx >> 4;
            int k = idx & 15;
            int gr = row0 + m;
            float v = 0.f;
            if (gr < nrows && (k0 + k) < K) v = A[(size_t)gr * lda + k0 + k];
            As[k][m] = v;
        }
#pragma unroll
        for (int i = 0; i < 4; i++) {
            int idx = tid + i * 256;
            int k = idx >> 6;
            int j = idx & 63;
            float v = 0.f;
            if ((k0 + k) < K && (colblk + j) < ncols) v = B[(size_t)(k0 + k) * ldb + colblk + j];
            Bs[k][j] = v;
        }
        __syncthreads();
#pragma unroll
        for (int k = 0; k < 16; k++) {
            float av[4], bv[4];
#pragma unroll
            for (int i = 0; i < 4; i++) av[i] = As[k][tm * 4 + i];
#pragma unroll
            for (int j = 0; j < 4; j++) bv[j] = Bs[k][tn * 4 + j];
#pragma unroll
            for (int i = 0; i < 4; i++)
#pragma unroll
                for (int j = 0; j < 4; j++) acc[i][j] += av[i] * bv[j];
        }
        __syncthreads();
    }
#pragma unroll
    for (int i = 0; i < 4; i++) {
        int gr = row0 + tm * 4 + i;
        if (gr >= nrows) continue;
#pragma unroll
        for (int j = 0; j < 4; j++) {
            int gc = colblk + tn * 4 + j;
            if (gc < ncols) C[(size_t)gr * ldc + gc] = acc[i][j];
        }
    }
}

// ---------------- helpers ----------------
__device__ __forceinline__ void store8h(f16* p, const float o[8]) {
    f16x8 v;
#pragma unroll
    for (int k = 0; k < 8; k++) v[k] = (f16)o[k];
    *(f16x8*)p = v;
}

__device__ __forceinline__ float dot8_lrelu(const uint4& vr, const f16x2 u2[4],
                                            const f16x2 a2[4]) {
    const f16x2* vp = (const f16x2*)&vr;
    float p = 0.f;
#pragma unroll
    for (int k = 0; k < 4; k++) {
        f16x2 w = u2[k] + vp[k];
        f16x2 lr = __builtin_elementwise_max(w, w * (_Float16)0.2f);
#if __has_builtin(__builtin_amdgcn_fdot2)
        p = __builtin_amdgcn_fdot2(lr, a2[k], p, false);
#else
        p = fmaf((float)lr[0], (float)a2[k][0], p);
        p = fmaf((float)lr[1], (float)a2[k][1], p);
#endif
    }
    return p;
}

// ---------------- layer-1 edge/aggregation (fused, single launch) ----------------
__global__ void edge_l1(const int* __restrict__ offsets, const int* __restrict__ dsts,
                        const f16* __restrict__ h, const f16* __restrict__ uv,
                        const float* __restrict__ a, f16* __restrict__ x2, int n) {
    const int lane = threadIdx.x & 63;
    const int wave = threadIdx.x >> 6;
    const int t = blockIdx.x * (blockDim.x >> 6) + wave;
    if (t >= n) return;
    const int head = lane >> 3;
    const int sub = lane & 7;
    const unsigned voff = head * 128 + 64 + sub * 8;
    const unsigned uoff = head * 128 + sub * 8;
    const unsigned hoff = lane * 8;

    f16x2 u2[4], a2[4];
    {
        uint4 ur = *(const uint4*)(uv + (size_t)t * 1024 + uoff);
        const f16x2* up = (const f16x2*)&ur;
#pragma unroll
        for (int k = 0; k < 4; k++) u2[k] = up[k];
        const float4* ap = (const float4*)(a + hoff);
        float4 a0 = ap[0], a1 = ap[1];
        a2[0] = f16x2{(f16)a0.x, (f16)a0.y};
        a2[1] = f16x2{(f16)a0.z, (f16)a0.w};
        a2[2] = f16x2{(f16)a1.x, (f16)a1.y};
        a2[3] = f16x2{(f16)a1.z, (f16)a1.w};
    }

    const int s0 = offsets[t], s1 = offsets[t + 1];
    float acc[8] = {0.f, 0.f, 0.f, 0.f, 0.f, 0.f, 0.f, 0.f};
    float rs = 0.f;

    for (int base = s0; base < s1; base += 64) {
        int cnt = s1 - base;
        if (cnt > 64) cnt = 64;
        int myd = (lane < cnt) ? dsts[base + lane] : 0;
        int d0 = __shfl(myd, 0, 64);
        uint4 vr = *(const uint4*)(uv + (size_t)(unsigned)d0 * 1024 + voff);
        uint4 hr = *(const uint4*)(h + (size_t)(unsigned)d0 * 512 + hoff);
        for (int j = 0; j < cnt; j++) {
            uint4 vr_n, hr_n;
            if (j + 1 < cnt) {
                int dn = __shfl(myd, j + 1, 64);
                vr_n = *(const uint4*)(uv + (size_t)(unsigned)dn * 1024 + voff);
                hr_n = *(const uint4*)(h + (size_t)(unsigned)dn * 512 + hoff);
            }
            float p = dot8_lrelu(vr, u2, a2);
            p += __shfl_xor(p, 1, 64);
            p += __shfl_xor(p, 2, 64);
            p += __shfl_xor(p, 4, 64);
            float wgt = __expf(p);
            rs += wgt;
            const f16* hp = (const f16*)&hr;
#pragma unroll
            for (int k = 0; k < 8; k++) acc[k] = fmaf(wgt, (float)hp[k], acc[k]);
            vr = vr_n;
            hr = hr_n;
        }
    }
    float inv = 1.f / rs;
    float o[8];
#pragma unroll
    for (int k = 0; k < 8; k++) {
        float hp = acc[k] * inv;
        float e1 = hp > 0.f ? hp : expm1f(hp);
        o[k] = e1 > 0.f ? e1 : expm1f(e1);
    }
    store8h(x2 + (size_t)t * 512 + hoff, o);
}

// ---------------- layer-2 edge/aggregation: 8 edges in flight per wave ----------------
__global__ void edge_l2(const int* __restrict__ offsets, const int* __restrict__ dsts,
                        const f16x2* __restrict__ vh2, const float* __restrict__ uv2,
                        const float* __restrict__ a_out, float* __restrict__ out, int n) {
    const int lane = threadIdx.x & 63;
    const int wave = threadIdx.x >> 6;
    const int t = blockIdx.x * (blockDim.x >> 6) + wave;
    if (t >= n) return;
    const int g = lane >> 3;
    const int s = lane & 7;
    float u5[5], a5[5];
#pragma unroll
    for (int k = 0; k < 5; k++) {
        u5[k] = uv2[(size_t)t * 80 + s * 5 + k];
        a5[k] = a_out[s * 5 + k];
    }
    const int s0 = offsets[t], s1 = offsets[t + 1];
    float acc[5] = {0.f, 0.f, 0.f, 0.f, 0.f};
    float rs = 0.f;
    for (int base = s0; base < s1; base += 64) {
        int cnt = s1 - base;
        if (cnt > 64) cnt = 64;
        int myd = (lane < cnt) ? dsts[base + lane] : 0;
        for (int j8 = 0; j8 < cnt; j8 += 8) {
            int eidx = j8 + g;
            bool active = eidx < cnt;
            int d = __shfl(myd, active ? eidx : 0, 64);
            f16x2 vh[5];
            const f16x2* vp = vh2 + (size_t)(unsigned)d * 40 + s * 5;
#pragma unroll
            for (int k = 0; k < 5; k++) vh[k] = vp[k];
            float p = 0.f;
#pragma unroll
            for (int k = 0; k < 5; k++) {
                float w = u5[k] + (float)vh[k][0];
                p = fmaf(a5[k], fmaxf(w, 0.2f * w), p);
            }
            p += __shfl_xor(p, 1, 64);
            p += __shfl_xor(p, 2, 64);
            p += __shfl_xor(p, 4, 64);
            float wgt = active ? __expf(p) : 0.f;
            rs += wgt;
#pragma unroll
            for (int k = 0; k < 5; k++) acc[k] = fmaf(wgt, (float)vh[k][1], acc[k]);
        }
    }
    rs += __shfl_xor(rs, 8, 64);
    rs += __shfl_xor(rs, 16, 64);
    rs += __shfl_xor(rs, 32, 64);
#pragma unroll
    for (int k = 0; k < 5; k++) {
        acc[k] += __shfl_xor(acc[k], 8, 64);
        acc[k] += __shfl_xor(acc[k], 16, 64);
        acc[k] += __shfl_xor(acc[k], 32, 64);
    }
    if (g == 0) {
        float inv = 1.f / rs;
#pragma unroll
        for (int k = 0; k < 5; k++) {
            float hp = acc[k] * inv;
            out[(size_t)t * 40 + s * 5 + k] = hp > 0.f ? hp : expm1f(hp);
        }
    }
}

// ---------------- launch ----------------
extern "C" void kernel_launch(void* const* d_in, const int* in_sizes, int n_in,
                              void* d_out, int out_size, void* d_ws, size_t ws_size,
                              hipStream_t stream) {
    const float* x         = (const float*)d_in[0];
    const int*   edge      = (const int*)d_in[1];
    const float* W         = (const float*)d_in[2];
    const float* W_pair    = (const float*)d_in[3];
    const float* a         = (const float*)d_in[4];
    const float* W_out     = (const float*)d_in[5];
    const float* W_pair_out= (const float*)d_in[6];
    const float* a_out     = (const float*)d_in[7];
    float* out = (float*)d_out;

    const int n  = in_sizes[0] / FEAT;   // 50000
    const int ne = in_sizes[1] / 2;      // 1,650,000
    const int* srcArr = edge;
    const int* dstArr = edge + ne;

    char* ws = (char*)d_ws;
    size_t off = 0;
    auto alloc = [&](size_t bytes) -> void* {
        void* p = ws + off;
        off = (off + bytes + 255) & ~(size_t)255;
        return p;
    };
    f16* h    = (f16*)alloc((size_t)n * 512 * sizeof(f16));      // [N][512]; later aliased by h2/uv2
    f16* uv   = (f16*)alloc((size_t)n * 1024 * sizeof(f16));     // [N][1024]
    f16* x2   = (f16*)alloc((size_t)n * 512 * sizeof(f16));      // [N][512]
    f16x2* vh2 = (f16x2*)alloc((size_t)n * 40 * sizeof(f16x2));  // [N][40] {v2,h2}
    uint2* pairs = (uint2*)alloc((size_t)ne * sizeof(uint2));    // [E] (src,dst) bucket-ordered
    f16* Wh_t = (f16*)alloc(512 * 512 * sizeof(f16));
    f16* Bp_t = (f16*)alloc(8 * 128 * 64 * sizeof(f16));
    f16* Wo_t = (f16*)alloc(40 * 512 * sizeof(f16));
    float* B2p = (float*)alloc(40 * 80 * sizeof(float));
    int* counts  = (int*)alloc((size_t)n * sizeof(int));
    int* offsets = (int*)alloc((size_t)(n + 1) * sizeof(int));
    int* bcursor = (int*)alloc(1024 * sizeof(int));
    int* partial = (int*)alloc(1024 * sizeof(int));
    int* dsts    = (int*)alloc((size_t)ne * sizeof(int));
    float* h2  = (float*)h;                          // h dead after edge_l1
    float* uv2 = (float*)((char*)h + (size_t)n * 40 * sizeof(float));

    const int nb = (n + 255) / 256;             // 196 scan blocks
    const int nbuckets = (n + BKT - 1) / BKT;   // 196
    const int msBlocks = (ne + STAGECAP - 1) / STAGECAP;   // 248

    // CSR build: hist -> scan -> multisplit (bucket order) -> LDS place (target order)
    hipMemsetAsync(counts, 0, (size_t)n * sizeof(int), stream);
    hist_kernel<<<2048, 256, 0, stream>>>(srcArr, counts, ne);
    scan_partial<<<nb, 256, 0, stream>>>(counts, partial, n);
    scan_top<<<1, 1024, 0, stream>>>(partial, nb);
    scan_final<<<nb, 256, 0, stream>>>(counts, partial, offsets, n);
    binit<<<(nbuckets + 255) / 256, 256, 0, stream>>>(offsets, bcursor, nbuckets);
    multisplit<<<msBlocks, 256, 0, stream>>>(srcArr, dstArr, bcursor, pairs, ne, nbuckets);
    lds_place<<<nbuckets, 256, 0, stream>>>(pairs, offsets, dsts, n);

    // weight packs (single launch)
    const int packTotal = 512 * 512 + 8 * 128 * 64 + 40 * 512 + 40 * 80;
    pack_all<<<(packTotal + 255) / 256, 256, 0, stream>>>(
        W, W_pair, W_out, W_pair_out, Wh_t, Bp_t, Wo_t, B2p);

    const int mBlocks = (n + 127) / 128;   // 391

    // h = f16(x) @ Wh   [N,512] f16
    gemm_mfma<float, f16><<<dim3(mBlocks, 1, 4), 256, 0, stream>>>(
        x, 512, 0, 0, Wh_t, 0, 512, h, 512, 0, n, 512);

    // uv = per-head h @ Bp_t   (K=64)
    gemm_mfma<f16, f16><<<dim3(mBlocks, 8, 1), 256, 0, stream>>>(
        h, 512, 0, 64, Bp_t, 128L * 64, 64, uv, 1024, 128, n, 128);

    // layer-1 edge phase -> x2 (single launch)
    edge_l1<<<dim3((n + 3) / 4), 256, 0, stream>>>(offsets, dsts, h, uv, a, x2, n);

    // h2 = x2 @ W_out  [N,40] f32 (aliases h)
    gemm_mfma<f16, float><<<dim3(mBlocks, 1, 1), 256, 0, stream>>>(
        x2, 512, 0, 0, Wo_t, 0, 512, h2, 40, 0, n, 40);

    // uv2 = h2 @ B2p  [N,80] f32
    gemm_kernel<<<dim3((n + 63) / 64, 1, 2), 256, 0, stream>>>(
        h2, 40, B2p, 80, uv2, 80, n, 40, 80);

    // pack interleaved {v2,h2} f16 pairs for edge_l2
    pack_vh2<<<(n * 40 + 255) / 256, 256, 0, stream>>>(h2, uv2, vh2, n * 40);

    // layer-2 edge phase -> out
    edge_l2<<<dim3((n + 3) / 4), 256, 0, stream>>>(offsets, dsts, vh2, uv2, a_out, out, n);
}